// Round 1
// 1914.451 us; speedup vs baseline: 1.0774x; 1.0774x over previous
//
#include <hip/hip_runtime.h>
#include <hip/hip_bf16.h>
#include <stdint.h>

#define N_NODES 2048
#define N_EDGES 32768

using short8  = __attribute__((ext_vector_type(8))) short;
using floatx4 = __attribute__((ext_vector_type(4))) float;

__device__ __forceinline__ unsigned short f2bf(float f) {
  unsigned u = __float_as_uint(f);
  unsigned r = (u + 0x7fffu + ((u >> 16) & 1u)) >> 16;
  return (unsigned short)r;
}
__device__ __forceinline__ float wave_sum(float v) {
  #pragma unroll
  for (int o = 32; o > 0; o >>= 1) v += __shfl_xor(v, o);
  return v;
}
__device__ __forceinline__ float wave_max(float v) {
  #pragma unroll
  for (int o = 32; o > 0; o >>= 1) v = fmaxf(v, __shfl_xor(v, o));
  return v;
}

// ---------------------------------------------------------------------------
// feat fp32 -> bf16 (layer-1 GEMM A operand)
// ---------------------------------------------------------------------------
__global__ __launch_bounds__(256) void cast_feat(
    const float* __restrict__ in, unsigned short* __restrict__ out, int n4)
{
  int i = blockIdx.x * 256 + threadIdx.x;
  if (i < n4) {
    float4 v = ((const float4*)in)[i];
    ushort4 o;
    o.x = f2bf(v.x); o.y = f2bf(v.y); o.z = f2bf(v.z); o.w = f2bf(v.w);
    ((ushort4*)out)[i] = o;
  }
}

// ---------------------------------------------------------------------------
// W [gridDim.z][Fin][512] (fp32) -> Wt [gridDim.z][512][Fin] (bf16), 64x64 tiles
// ---------------------------------------------------------------------------
__global__ __launch_bounds__(256) void transpose_w(
    const float* __restrict__ W, unsigned short* __restrict__ Wt, int Fin)
{
  __shared__ unsigned short tile[64][68];  // +4 pad breaks pow2 stride
  const int h  = blockIdx.z;
  const int k0 = blockIdx.x * 64;
  const int d0 = blockIdx.y * 64;
  const int t  = threadIdx.x;
  const float*    Wh  = W  + (size_t)h * Fin * 512;
  unsigned short* Wth = Wt + (size_t)h * 512 * Fin;

  const int dl = (t & 15) * 4;   // 4 d-elems (16 B fp32) per thread
  const int kr = t >> 4;
  #pragma unroll
  for (int p = 0; p < 4; ++p) {
    int k = kr + p * 16;
    float4 v = *(const float4*)(Wh + (size_t)(k0 + k) * 512 + d0 + dl);
    ushort4 b;
    b.x = f2bf(v.x); b.y = f2bf(v.y); b.z = f2bf(v.z); b.w = f2bf(v.w);
    *(ushort4*)&tile[k][dl] = b;
  }
  __syncthreads();
  const int kl = (t & 15) * 4;   // 4 k-elems, contiguous in Wt row
  const int dr = t >> 4;
  #pragma unroll
  for (int p = 0; p < 4; ++p) {
    int d = dr + p * 16;
    ushort4 v;
    v.x = tile[kl + 0][d];
    v.y = tile[kl + 1][d];
    v.z = tile[kl + 2][d];
    v.w = tile[kl + 3][d];
    *(ushort4*)(Wth + (size_t)(d0 + d) * Fin + k0 + kl) = v;
  }
}

// ---------------------------------------------------------------------------
// C[M x HD](fp32), cols [(h0+hloc)*512 + nloc ..) = A[M x K] @ Bt[hloc][512][K]
// m97 structure: 128x128 tile, BK=32, 4 waves, global_load_lds width 16.
// Split-K: blockIdx.z selects a K-chunk of length klen; if gridDim.z>1 the
// C-write becomes atomicAdd (C must be pre-zeroed).
// ---------------------------------------------------------------------------
__global__ __launch_bounds__(256) void gemm_bt(
    const unsigned short* __restrict__ A,
    const unsigned short* __restrict__ Bt,
    float* __restrict__ C, int K, int HD, int h0, int klen)
{
  __shared__ unsigned short As[128 * 32];
  __shared__ unsigned short Bs[128 * 32];
  const int tid  = threadIdx.x;
  const int w    = tid >> 6;
  const int lane = tid & 63;
  const int mt   = blockIdx.x;
  const int nt   = blockIdx.y;
  const int hloc = nt >> 2;
  const int nloc = (nt & 3) << 7;
  const int kstart = blockIdx.z * klen;

  const unsigned short* Ab = A  + (size_t)mt * 128 * K;
  const unsigned short* Bb = Bt + (size_t)hloc * 512 * K + (size_t)nloc * K;

  const int srow = lane >> 2;          // 16 rows per staging instr
  const int scol = (lane & 3) << 3;    // 8-elem chunks
  const unsigned short* ga = Ab + (size_t)(w * 32 + srow) * K + scol + kstart;
  const unsigned short* gb = Bb + (size_t)(w * 32 + srow) * K + scol + kstart;

  floatx4 acc[4][4];
  #pragma unroll
  for (int i = 0; i < 4; ++i)
    #pragma unroll
    for (int j = 0; j < 4; ++j)
      acc[i][j] = (floatx4){0.f, 0.f, 0.f, 0.f};

  const int quad = lane >> 4;
  const int l16  = lane & 15;
  const int wm   = (w >> 1) << 6;
  const int wn   = (w & 1) << 6;

  for (int kb = 0; kb < klen; kb += 32) {
    __builtin_amdgcn_global_load_lds(
        (const __attribute__((address_space(1))) void*)ga,
        (__attribute__((address_space(3))) void*)&As[w * 1024], 16, 0, 0);
    __builtin_amdgcn_global_load_lds(
        (const __attribute__((address_space(1))) void*)(ga + (size_t)16 * K),
        (__attribute__((address_space(3))) void*)&As[w * 1024 + 512], 16, 0, 0);
    __builtin_amdgcn_global_load_lds(
        (const __attribute__((address_space(1))) void*)gb,
        (__attribute__((address_space(3))) void*)&Bs[w * 1024], 16, 0, 0);
    __builtin_amdgcn_global_load_lds(
        (const __attribute__((address_space(1))) void*)(gb + (size_t)16 * K),
        (__attribute__((address_space(3))) void*)&Bs[w * 1024 + 512], 16, 0, 0);
    ga += 32; gb += 32;
    __syncthreads();

    short8 af[4], bfr[4];
    #pragma unroll
    for (int mi = 0; mi < 4; ++mi)
      af[mi] = *(const short8*)&As[(wm + mi * 16 + l16) * 32 + quad * 8];
    #pragma unroll
    for (int ni = 0; ni < 4; ++ni)
      bfr[ni] = *(const short8*)&Bs[(wn + ni * 16 + l16) * 32 + quad * 8];
    #pragma unroll
    for (int mi = 0; mi < 4; ++mi)
      #pragma unroll
      for (int ni = 0; ni < 4; ++ni)
        acc[mi][ni] = __builtin_amdgcn_mfma_f32_16x16x32_bf16(
            af[mi], bfr[ni], acc[mi][ni], 0, 0, 0);
    __syncthreads();
  }

  // C/D layout (m89/m91 verified): col = lane&15, row = quad*4 + reg
  float* Cb = C + (size_t)(mt * 128) * HD + (h0 + hloc) * 512 + nloc;
  if (gridDim.z > 1) {
    #pragma unroll
    for (int mi = 0; mi < 4; ++mi)
      #pragma unroll
      for (int ni = 0; ni < 4; ++ni)
        #pragma unroll
        for (int r = 0; r < 4; ++r) {
          int row = wm + mi * 16 + quad * 4 + r;
          int col = wn + ni * 16 + l16;
          atomicAdd(&Cb[(size_t)row * HD + col], acc[mi][ni][r]);
        }
  } else {
    #pragma unroll
    for (int mi = 0; mi < 4; ++mi)
      #pragma unroll
      for (int ni = 0; ni < 4; ++ni)
        #pragma unroll
        for (int r = 0; r < 4; ++r) {
          int row = wm + mi * 16 + quad * 4 + r;
          int col = wn + ni * 16 + l16;
          Cb[(size_t)row * HD + col] = acc[mi][ni][r];
        }
  }
}

// ---------------------------------------------------------------------------
// s_src[n,h] = z[n,h,:]·a[h,0:512],  s_dst[n,h] = z[n,h,:]·a[h,512:1024]
// a is fp32. One wave per (n,h).
// ---------------------------------------------------------------------------
__global__ __launch_bounds__(64) void sdot_kernel(
    const float* __restrict__ z, const float* __restrict__ a,
    float* __restrict__ ssrc, float* __restrict__ sdst, int H)
{
  const int idx  = blockIdx.x;
  const int n    = idx / H;
  const int h    = idx % H;
  const int lane = threadIdx.x;
  const float4* zr = (const float4*)(z + (size_t)n * H * 512 + h * 512 + lane * 8);
  float4 z0 = zr[0], z1 = zr[1];
  const float4* as = (const float4*)(a + (size_t)h * 1024 + lane * 8);
  const float4* ad = (const float4*)(a + (size_t)h * 1024 + 512 + lane * 8);
  float4 a0 = as[0], a1 = as[1];
  float4 b0 = ad[0], b1 = ad[1];
  float s1 = z0.x*a0.x + z0.y*a0.y + z0.z*a0.z + z0.w*a0.w
           + z1.x*a1.x + z1.y*a1.y + z1.z*a1.z + z1.w*a1.w;
  float s2 = z0.x*b0.x + z0.y*b0.y + z0.z*b0.z + z0.w*b0.w
           + z1.x*b1.x + z1.y*b1.y + z1.z*b1.z + z1.w*b1.w;
  s1 = wave_sum(s1);
  s2 = wave_sum(s2);
  if (lane == 0) { ssrc[idx] = s1; sdst[idx] = s2; }
}

// ---------------------------------------------------------------------------
// CSR build (dst shared across all 4 layers)
// ---------------------------------------------------------------------------
__global__ void count_k(const int* __restrict__ dst, int* __restrict__ cnt) {
  int e = blockIdx.x * 256 + threadIdx.x;
  if (e < N_EDGES) atomicAdd(&cnt[dst[e]], 1);
}

__global__ __launch_bounds__(256) void scan_k(
    const int* __restrict__ cnt, int* __restrict__ offs, int* __restrict__ cur)
{
  __shared__ int part[256];
  int t = threadIdx.x;
  int loc[8]; int s = 0;
  #pragma unroll
  for (int j = 0; j < 8; ++j) { loc[j] = s; s += cnt[t * 8 + j]; }
  part[t] = s;
  __syncthreads();
  for (int d = 1; d < 256; d <<= 1) {
    int v = (t >= d) ? part[t - d] : 0;
    __syncthreads();
    part[t] += v;
    __syncthreads();
  }
  int base = (t == 0) ? 0 : part[t - 1];
  #pragma unroll
  for (int j = 0; j < 8; ++j) {
    int o = base + loc[j];
    offs[t * 8 + j] = o;
    cur[t * 8 + j]  = o;
  }
  if (t == 255) offs[2048] = part[255];
}

__global__ void scatter_k(const int* __restrict__ dst, const int* __restrict__ srcv,
                          int* __restrict__ cur, int* __restrict__ esrc) {
  int e = blockIdx.x * 256 + threadIdx.x;
  if (e < N_EDGES) {
    int p = atomicAdd(&cur[dst[e]], 1);
    esrc[p] = srcv[e];
  }
}

// ---------------------------------------------------------------------------
// Fused softmax-attention + aggregation. One wave per (n, h).
// outb (bf16, intermediate) or outf (fp32, final) — exactly one non-null.
// ---------------------------------------------------------------------------
__global__ __launch_bounds__(64) void attn_agg(
    const float* __restrict__ z, const float* __restrict__ ssrc,
    const float* __restrict__ sdst, const int* __restrict__ offs,
    const int* __restrict__ esrc, unsigned short* __restrict__ outb,
    float* __restrict__ outf, int H)
{
  const int n = blockIdx.x, h = blockIdx.y, lane = threadIdx.x;
  const int s0 = offs[n], s1 = offs[n + 1];
  const float sd = sdst[n * H + h];

  float m = -3e38f;
  for (int i = s0 + lane; i < s1; i += 64) {
    float s = ssrc[esrc[i] * H + h] + sd;
    s = (s > 0.f) ? s : s * 0.01f;
    m = fmaxf(m, s);
  }
  m = wave_max(m);

  float den = 0.f;
  for (int i = s0 + lane; i < s1; i += 64) {
    float s = ssrc[esrc[i] * H + h] + sd;
    s = (s > 0.f) ? s : s * 0.01f;
    den += __expf(s - m);
  }
  den = wave_sum(den);
  const float inv = 1.f / den;

  float acc[8] = {0.f, 0.f, 0.f, 0.f, 0.f, 0.f, 0.f, 0.f};
  const float* zb = z + (size_t)h * 512 + lane * 8;
  for (int i = s0; i < s1; ++i) {
    int se = esrc[i];
    float s = ssrc[se * H + h] + sd;
    s = (s > 0.f) ? s : s * 0.01f;
    float alpha = __expf(s - m) * inv;
    const float4* zr = (const float4*)(zb + (size_t)se * H * 512);
    float4 q0 = zr[0], q1 = zr[1];
    acc[0] += alpha * q0.x; acc[1] += alpha * q0.y;
    acc[2] += alpha * q0.z; acc[3] += alpha * q0.w;
    acc[4] += alpha * q1.x; acc[5] += alpha * q1.y;
    acc[6] += alpha * q1.z; acc[7] += alpha * q1.w;
  }

  const size_t base = (size_t)n * H * 512 + h * 512 + lane * 8;
  if (outf) {
    float4 o0 = {acc[0], acc[1], acc[2], acc[3]};
    float4 o1 = {acc[4], acc[5], acc[6], acc[7]};
    *(float4*)(outf + base)     = o0;
    *(float4*)(outf + base + 4) = o1;
  } else {
    uint4 pk;
    pk.x = (unsigned)f2bf(acc[0]) | ((unsigned)f2bf(acc[1]) << 16);
    pk.y = (unsigned)f2bf(acc[2]) | ((unsigned)f2bf(acc[3]) << 16);
    pk.z = (unsigned)f2bf(acc[4]) | ((unsigned)f2bf(acc[5]) << 16);
    pk.w = (unsigned)f2bf(acc[6]) | ((unsigned)f2bf(acc[7]) << 16);
    *(uint4*)(outb + base) = pk;
  }
}

// ---------------------------------------------------------------------------
extern "C" void kernel_launch(void* const* d_in, const int* in_sizes, int n_in,
                              void* d_out, int out_size, void* d_ws, size_t ws_size,
                              hipStream_t stream)
{
  (void)in_sizes; (void)n_in; (void)out_size;
  const float* feat = (const float*)d_in[0];
  const float* W1   = (const float*)d_in[1];
  const float* a1   = (const float*)d_in[2];
  const float* W2   = (const float*)d_in[3];
  const float* a2   = (const float*)d_in[4];
  const float* W3   = (const float*)d_in[5];
  const float* a3   = (const float*)d_in[6];
  const float* W4   = (const float*)d_in[7];
  const float* a4   = (const float*)d_in[8];
  const int* src = (const int*)d_in[9];
  const int* dst = (const int*)d_in[10];
  float* out = (float*)d_out;

  // Workspace layout chosen at runtime from ws_size.
  //  16-head path (one GEMM launch per big layer, 1024 blocks = 4 blocks/CU):
  //    wt 134 MB | z 67 MB | x 33.5 MB | x0 2 MB | small  ≈ 226.5 MiB
  //  8-head fallback (two groups, current behavior):
  //    wt 67 MB  | z 67 MB | x 33.5 MB | x0 2 MB | small  ≈ 162.5 MiB
  // Single x buffer: layer L's GEMM fully consumes x before attn_agg
  // rewrites it (stream-ordered), so ping-pong buffers are unnecessary.
  const size_t WT16 = (size_t)16 * 512 * 8192 * 2;  // 134,217,728
  const size_t WT8  = WT16 / 2;
  const size_t ZSZ  = (size_t)N_NODES * 16 * 512 * 4;   // 67,108,864
  const size_t XSZ  = (size_t)N_NODES * 8192 * 2;       // 33,554,432
  const size_t X0SZ = (size_t)N_NODES * 512 * 2;        //  2,097,152
  const size_t SMALL = 131072 + 131072 + 8192 + 8448 + 8192 + 131072;
  const size_t NEED16 = WT16 + ZSZ + XSZ + X0SZ + SMALL;

  const int ngroups = (ws_size >= NEED16) ? 1 : 2;
  const size_t wtsz = (ngroups == 1) ? WT16 : WT8;

  char* ws = (char*)d_ws;
  unsigned short* wt = (unsigned short*)ws;
  float* z           = (float*)(ws + wtsz);
  unsigned short* x  = (unsigned short*)(ws + wtsz + ZSZ);
  unsigned short* x0 = (unsigned short*)(ws + wtsz + ZSZ + XSZ);
  char* sm           = ws + wtsz + ZSZ + XSZ + X0SZ;
  float* ssrc        = (float*)(sm);
  float* sdst        = (float*)(sm + 131072);
  int* cnt           = (int*)(sm + 262144);
  int* offs          = (int*)(sm + 270336);
  int* cur           = (int*)(sm + 278784);
  int* esrc          = (int*)(sm + 286976);

  // CSR by dst (constant across layers)
  hipMemsetAsync(cnt, 0, N_NODES * sizeof(int), stream);
  count_k<<<N_EDGES / 256, 256, 0, stream>>>(dst, cnt);
  scan_k<<<1, 256, 0, stream>>>(cnt, offs, cur);
  scatter_k<<<N_EDGES / 256, 256, 0, stream>>>(dst, src, cur, esrc);

  // feat fp32 -> bf16
  cast_feat<<<1024, 256, 0, stream>>>(feat, x0, N_NODES * 512 / 4);

  // One GAT layer (GEMM part). Fin: input dim; H: heads; xin: bf16 [2048][Fin].
  auto run_gemm = [&](const float* W, const unsigned short* xin,
                      int Fin, int H, int ksplit) {
    const int groups = (H == 16) ? ngroups : 1;
    const int hpg = H / groups;
    for (int g = 0; g < groups; ++g) {
      transpose_w<<<dim3(Fin / 64, 8, hpg), 256, 0, stream>>>(
          W + (size_t)g * hpg * Fin * 512, wt, Fin);
      if (ksplit > 1)
        hipMemsetAsync(z, 0, (size_t)N_NODES * H * 512 * sizeof(float), stream);
      gemm_bt<<<dim3(16, hpg * 4, ksplit), 256, 0, stream>>>(
          xin, wt, z, Fin, H * 512, g * hpg, Fin / ksplit);
    }
  };

  // Layer 1: Fin=512, H=16
  run_gemm(W1, x0, 512, 16, 1);
  sdot_kernel<<<N_NODES * 16, 64, 0, stream>>>(z, a1, ssrc, sdst, 16);
  attn_agg<<<dim3(N_NODES, 16), 64, 0, stream>>>(z, ssrc, sdst, offs, esrc,
                                                 x, nullptr, 16);

  // Layer 2: Fin=8192, H=16
  run_gemm(W2, x, 8192, 16, 1);
  sdot_kernel<<<N_NODES * 16, 64, 0, stream>>>(z, a2, ssrc, sdst, 16);
  attn_agg<<<dim3(N_NODES, 16), 64, 0, stream>>>(z, ssrc, sdst, offs, esrc,
                                                 x, nullptr, 16);

  // Layer 3: Fin=8192, H=16
  run_gemm(W3, x, 8192, 16, 1);
  sdot_kernel<<<N_NODES * 16, 64, 0, stream>>>(z, a3, ssrc, sdst, 16);
  attn_agg<<<dim3(N_NODES, 16), 64, 0, stream>>>(z, ssrc, sdst, offs, esrc,
                                                 x, nullptr, 16);

  // Layer 4: Fin=8192, H=1 — split-K x8 (grid 16x4x8 = 512 blocks, atomicAdd)
  run_gemm(W4, x, 8192, 1, 8);
  sdot_kernel<<<N_NODES, 64, 0, stream>>>(z, a4, ssrc, sdst, 1);
  attn_agg<<<dim3(N_NODES, 1), 64, 0, stream>>>(z, ssrc, sdst, offs, esrc,
                                                nullptr, out, 1);
}

// Round 2
// 1539.553 us; speedup vs baseline: 1.3398x; 1.2435x over previous
//
#include <hip/hip_runtime.h>
#include <hip/hip_bf16.h>
#include <stdint.h>

#define N_NODES 2048
#define N_EDGES 32768

using short8  = __attribute__((ext_vector_type(8))) short;
using floatx4 = __attribute__((ext_vector_type(4))) float;

__device__ __forceinline__ unsigned short f2bf(float f) {
  unsigned u = __float_as_uint(f);
  unsigned r = (u + 0x7fffu + ((u >> 16) & 1u)) >> 16;
  return (unsigned short)r;
}
__device__ __forceinline__ float wave_sum(float v) {
  #pragma unroll
  for (int o = 32; o > 0; o >>= 1) v += __shfl_xor(v, o);
  return v;
}
__device__ __forceinline__ float wave_max(float v) {
  #pragma unroll
  for (int o = 32; o > 0; o >>= 1) v = fmaxf(v, __shfl_xor(v, o));
  return v;
}

// ---------------------------------------------------------------------------
// feat fp32 -> bf16 (layer-1 GEMM A operand)
// ---------------------------------------------------------------------------
__global__ __launch_bounds__(256) void cast_feat(
    const float* __restrict__ in, unsigned short* __restrict__ out, int n4)
{
  int i = blockIdx.x * 256 + threadIdx.x;
  if (i < n4) {
    float4 v = ((const float4*)in)[i];
    ushort4 o;
    o.x = f2bf(v.x); o.y = f2bf(v.y); o.z = f2bf(v.z); o.w = f2bf(v.w);
    ((ushort4*)out)[i] = o;
  }
}

// ---------------------------------------------------------------------------
// W [gridDim.z][Fin][512] (fp32) -> Wt [gridDim.z][512][Fin] (bf16), 64x64 tiles
// ---------------------------------------------------------------------------
__global__ __launch_bounds__(256) void transpose_w(
    const float* __restrict__ W, unsigned short* __restrict__ Wt, int Fin)
{
  __shared__ unsigned short tile[64][68];  // +4 pad breaks pow2 stride
  const int h  = blockIdx.z;
  const int k0 = blockIdx.x * 64;
  const int d0 = blockIdx.y * 64;
  const int t  = threadIdx.x;
  const float*    Wh  = W  + (size_t)h * Fin * 512;
  unsigned short* Wth = Wt + (size_t)h * 512 * Fin;

  const int dl = (t & 15) * 4;   // 4 d-elems (16 B fp32) per thread
  const int kr = t >> 4;
  #pragma unroll
  for (int p = 0; p < 4; ++p) {
    int k = kr + p * 16;
    float4 v = *(const float4*)(Wh + (size_t)(k0 + k) * 512 + d0 + dl);
    ushort4 b;
    b.x = f2bf(v.x); b.y = f2bf(v.y); b.z = f2bf(v.z); b.w = f2bf(v.w);
    *(ushort4*)&tile[k][dl] = b;
  }
  __syncthreads();
  const int kl = (t & 15) * 4;   // 4 k-elems, contiguous in Wt row
  const int dr = t >> 4;
  #pragma unroll
  for (int p = 0; p < 4; ++p) {
    int d = dr + p * 16;
    ushort4 v;
    v.x = tile[kl + 0][d];
    v.y = tile[kl + 1][d];
    v.z = tile[kl + 2][d];
    v.w = tile[kl + 3][d];
    *(ushort4*)(Wth + (size_t)(d0 + d) * Fin + k0 + kl) = v;
  }
}

// ---------------------------------------------------------------------------
// 256x256-tile 8-wave phased GEMM (T2+T3+T4+T5 port, ring-of-4 LDS slots).
// C[M x ldc](fp32), cols [colbase + nt*256 ..) = A[M x K] @ Bt[nt*256.. rows][K]^T
// M = 2048 fixed (8 mt). Grid: 1-D, 8*ntn blocks, XCD-bijective swizzle.
// Per K-tile (BK=32): 2 phases x {ds_read, stage, barrier, lgkmcnt(0),
// setprio(1), 16 MFMA, setprio(0), barrier}; vmcnt(4) once per tile.
// Staging for tile t+2 issued during tile t (slot (t+2)&3 != slot t&3; its
// previous readers finished at tile t-2). LDS swizzle: 16B chunk c ^= (row>>1)&3,
// realized as pre-swizzled global source + swizzled ds_read address.
// ---------------------------------------------------------------------------
#define GLDS(g, l) __builtin_amdgcn_global_load_lds(                       \
    (const __attribute__((address_space(1))) void*)(g),                    \
    (__attribute__((address_space(3))) void*)(l), 16, 0, 0)

__global__ __launch_bounds__(512, 2) void gemm8(
    const unsigned short* __restrict__ A,
    const unsigned short* __restrict__ Bt,
    float* __restrict__ C, int K, int ldc, int colbase)
{
  __shared__ __align__(16) unsigned short lds_buf[4][16384];  // 4 slots x 32 KB

  const int tid  = threadIdx.x;
  const int w    = tid >> 6;          // wave 0..7
  const int lane = tid & 63;
  const int l16  = lane & 15;
  const int quad = lane >> 4;
  const int warp_m = w >> 2;          // 0..1
  const int warp_n = w & 3;           // 0..3

  // XCD-bijective swizzle (nwg multiple of 8)
  const int nwg = gridDim.x;
  const int cpx = nwg >> 3;
  const int wg  = (blockIdx.x & 7) * cpx + (blockIdx.x >> 3);
  const int mt  = wg & 7;
  const int nt  = wg >> 3;

  const int NT = K >> 5;              // K-tiles of 32

  // ---- staging addresses (global side pre-swizzled: chunk g = cl ^ f(row)) ----
  const int srow = lane >> 2;                                 // 0..15
  const int gch  = ((lane & 3) ^ ((lane >> 3) & 3)) * 8;      // swizzled k-elems
  const unsigned short* pa0 = A  + (size_t)(mt * 256 + w * 32 + srow) * K + gch;
  const unsigned short* pa1 = pa0 + (size_t)16 * K;
  const unsigned short* pb0 = Bt + (size_t)(nt * 256 + w * 32 + srow) * K + gch;
  const unsigned short* pb1 = pb0 + (size_t)16 * K;

  // ---- ds_read offsets (swizzled chunk = quad ^ ((l16>>1)&3)) ----
  const int fA   = (l16 >> 1) & 3;
  const int cswz = (quad ^ fA) * 8;                           // elems
  const int a_off = (warp_m * 128 + l16) * 32 + cswz;         // A part
  const int b_off = 8192 + (warp_n * 64 + l16) * 32 + cswz;   // B part (+32KB/2)

  floatx4 acc[8][4];
  #pragma unroll
  for (int i = 0; i < 8; ++i)
    #pragma unroll
    for (int j = 0; j < 4; ++j)
      acc[i][j] = (floatx4){0.f, 0.f, 0.f, 0.f};

  // ---- prologue: stage tiles 0 and 1 (slots 0,1); keep tile-1 in flight ----
  {
    unsigned short* dA0 = &lds_buf[0][w * 1024];
    unsigned short* dB0 = &lds_buf[0][8192 + w * 1024];
    GLDS(pa0, dA0); GLDS(pa1, dA0 + 512);
    GLDS(pb0, dB0); GLDS(pb1, dB0 + 512);
    unsigned short* dA1 = &lds_buf[1][w * 1024];
    unsigned short* dB1 = &lds_buf[1][8192 + w * 1024];
    GLDS(pa0 + 32, dA1); GLDS(pa1 + 32, dA1 + 512);
    GLDS(pb0 + 32, dB1); GLDS(pb1 + 32, dB1 + 512);
  }
  asm volatile("s_waitcnt vmcnt(4)");
  __builtin_amdgcn_s_barrier();
  __builtin_amdgcn_sched_barrier(0);

  // staging pointers start at tile 2
  const unsigned short* sa0 = pa0 + 64;
  const unsigned short* sa1 = pa1 + 64;
  const unsigned short* sb0 = pb0 + 64;
  const unsigned short* sb1 = pb1 + 64;

  for (int t = 0; t < NT; ++t) {
    const int s  = t & 3;
    const int s2 = (t + 2) & 3;
    const unsigned short* sl  = &lds_buf[s][0];
    const unsigned short* rdA = sl + a_off;
    const unsigned short* rdB = sl + b_off;
    const bool st = (t + 2) < NT;

    // ---------------- phase 1: mi 0..3 x ni 0..3 ----------------
    short8 af[4], bf4[4];
    #pragma unroll
    for (int mi = 0; mi < 4; ++mi)
      af[mi] = *(const short8*)(rdA + mi * 512);
    #pragma unroll
    for (int ni = 0; ni < 4; ++ni)
      bf4[ni] = *(const short8*)(rdB + ni * 512);
    if (st) {
      unsigned short* dA = &lds_buf[s2][w * 1024];
      GLDS(sa0, dA); GLDS(sa1, dA + 512);
    }
    __builtin_amdgcn_sched_barrier(0);
    __builtin_amdgcn_s_barrier();
    asm volatile("s_waitcnt lgkmcnt(0)");
    __builtin_amdgcn_sched_barrier(0);
    __builtin_amdgcn_s_setprio(1);
    #pragma unroll
    for (int mi = 0; mi < 4; ++mi)
      #pragma unroll
      for (int ni = 0; ni < 4; ++ni)
        acc[mi][ni] = __builtin_amdgcn_mfma_f32_16x16x32_bf16(
            af[mi], bf4[ni], acc[mi][ni], 0, 0, 0);
    __builtin_amdgcn_s_setprio(0);
    __builtin_amdgcn_sched_barrier(0);
    __builtin_amdgcn_s_barrier();
    __builtin_amdgcn_sched_barrier(0);

    // ---------------- phase 2: mi 4..7 x ni 0..3 (reuse bf4) ----------------
    short8 ag[4];
    #pragma unroll
    for (int mi = 0; mi < 4; ++mi)
      ag[mi] = *(const short8*)(rdA + (mi + 4) * 512);
    if (st) {
      unsigned short* dB = &lds_buf[s2][8192 + w * 1024];
      GLDS(sb0, dB); GLDS(sb1, dB + 512);
    }
    __builtin_amdgcn_sched_barrier(0);
    __builtin_amdgcn_s_barrier();
    asm volatile("s_waitcnt lgkmcnt(0)");
    __builtin_amdgcn_sched_barrier(0);
    __builtin_amdgcn_s_setprio(1);
    #pragma unroll
    for (int mi = 0; mi < 4; ++mi)
      #pragma unroll
      for (int ni = 0; ni < 4; ++ni)
        acc[mi + 4][ni] = __builtin_amdgcn_mfma_f32_16x16x32_bf16(
            ag[mi], bf4[ni], acc[mi + 4][ni], 0, 0, 0);
    __builtin_amdgcn_s_setprio(0);
    __builtin_amdgcn_sched_barrier(0);
    // tile boundary: tile t+1 must be landed; tile t+2 (4 loads) stays in flight
    if (st) asm volatile("s_waitcnt vmcnt(4)");
    else    asm volatile("s_waitcnt vmcnt(0)");
    __builtin_amdgcn_s_barrier();
    __builtin_amdgcn_sched_barrier(0);

    sa0 += 32; sa1 += 32; sb0 += 32; sb1 += 32;
  }

  // ---- epilogue: C/D layout col = l16, row = quad*4 + r (m89/m91 verified) ----
  float* Cb = C + (size_t)(mt * 256 + warp_m * 128) * ldc
                + colbase + nt * 256 + warp_n * 64;
  #pragma unroll
  for (int mi = 0; mi < 8; ++mi)
    #pragma unroll
    for (int ni = 0; ni < 4; ++ni)
      #pragma unroll
      for (int r = 0; r < 4; ++r) {
        int row = mi * 16 + quad * 4 + r;
        int col = ni * 16 + l16;
        Cb[(size_t)row * ldc + col] = acc[mi][ni][r];
      }
}

// ---------------------------------------------------------------------------
// Old 128x128 m97-structure GEMM — kept for layer 4 (N=512) with split-K.
// ---------------------------------------------------------------------------
__global__ __launch_bounds__(256) void gemm_bt(
    const unsigned short* __restrict__ A,
    const unsigned short* __restrict__ Bt,
    float* __restrict__ C, int K, int HD, int h0, int klen)
{
  __shared__ unsigned short As[128 * 32];
  __shared__ unsigned short Bs[128 * 32];
  const int tid  = threadIdx.x;
  const int w    = tid >> 6;
  const int lane = tid & 63;
  const int mt   = blockIdx.x;
  const int nt   = blockIdx.y;
  const int hloc = nt >> 2;
  const int nloc = (nt & 3) << 7;
  const int kstart = blockIdx.z * klen;

  const unsigned short* Ab = A  + (size_t)mt * 128 * K;
  const unsigned short* Bb = Bt + (size_t)hloc * 512 * K + (size_t)nloc * K;

  const int srow = lane >> 2;
  const int scol = (lane & 3) << 3;
  const unsigned short* ga = Ab + (size_t)(w * 32 + srow) * K + scol + kstart;
  const unsigned short* gb = Bb + (size_t)(w * 32 + srow) * K + scol + kstart;

  floatx4 acc[4][4];
  #pragma unroll
  for (int i = 0; i < 4; ++i)
    #pragma unroll
    for (int j = 0; j < 4; ++j)
      acc[i][j] = (floatx4){0.f, 0.f, 0.f, 0.f};

  const int quad = lane >> 4;
  const int l16  = lane & 15;
  const int wm   = (w >> 1) << 6;
  const int wn   = (w & 1) << 6;

  for (int kb = 0; kb < klen; kb += 32) {
    __builtin_amdgcn_global_load_lds(
        (const __attribute__((address_space(1))) void*)ga,
        (__attribute__((address_space(3))) void*)&As[w * 1024], 16, 0, 0);
    __builtin_amdgcn_global_load_lds(
        (const __attribute__((address_space(1))) void*)(ga + (size_t)16 * K),
        (__attribute__((address_space(3))) void*)&As[w * 1024 + 512], 16, 0, 0);
    __builtin_amdgcn_global_load_lds(
        (const __attribute__((address_space(1))) void*)gb,
        (__attribute__((address_space(3))) void*)&Bs[w * 1024], 16, 0, 0);
    __builtin_amdgcn_global_load_lds(
        (const __attribute__((address_space(1))) void*)(gb + (size_t)16 * K),
        (__attribute__((address_space(3))) void*)&Bs[w * 1024 + 512], 16, 0, 0);
    ga += 32; gb += 32;
    __syncthreads();

    short8 af[4], bfr[4];
    #pragma unroll
    for (int mi = 0; mi < 4; ++mi)
      af[mi] = *(const short8*)&As[(wm + mi * 16 + l16) * 32 + quad * 8];
    #pragma unroll
    for (int ni = 0; ni < 4; ++ni)
      bfr[ni] = *(const short8*)&Bs[(wn + ni * 16 + l16) * 32 + quad * 8];
    #pragma unroll
    for (int mi = 0; mi < 4; ++mi)
      #pragma unroll
      for (int ni = 0; ni < 4; ++ni)
        acc[mi][ni] = __builtin_amdgcn_mfma_f32_16x16x32_bf16(
            af[mi], bfr[ni], acc[mi][ni], 0, 0, 0);
    __syncthreads();
  }

  float* Cb = C + (size_t)(mt * 128) * HD + (h0 + hloc) * 512 + nloc;
  if (gridDim.z > 1) {
    #pragma unroll
    for (int mi = 0; mi < 4; ++mi)
      #pragma unroll
      for (int ni = 0; ni < 4; ++ni)
        #pragma unroll
        for (int r = 0; r < 4; ++r) {
          int row = wm + mi * 16 + quad * 4 + r;
          int col = wn + ni * 16 + l16;
          atomicAdd(&Cb[(size_t)row * HD + col], acc[mi][ni][r]);
        }
  } else {
    #pragma unroll
    for (int mi = 0; mi < 4; ++mi)
      #pragma unroll
      for (int ni = 0; ni < 4; ++ni)
        #pragma unroll
        for (int r = 0; r < 4; ++r) {
          int row = wm + mi * 16 + quad * 4 + r;
          int col = wn + ni * 16 + l16;
          Cb[(size_t)row * HD + col] = acc[mi][ni][r];
        }
  }
}

// ---------------------------------------------------------------------------
// s_src[n,h] = z[n,h,:]·a[h,0:512],  s_dst[n,h] = z[n,h,:]·a[h,512:1024]
// ---------------------------------------------------------------------------
__global__ __launch_bounds__(64) void sdot_kernel(
    const float* __restrict__ z, const float* __restrict__ a,
    float* __restrict__ ssrc, float* __restrict__ sdst, int H)
{
  const int idx  = blockIdx.x;
  const int n    = idx / H;
  const int h    = idx % H;
  const int lane = threadIdx.x;
  const float4* zr = (const float4*)(z + (size_t)n * H * 512 + h * 512 + lane * 8);
  float4 z0 = zr[0], z1 = zr[1];
  const float4* as = (const float4*)(a + (size_t)h * 1024 + lane * 8);
  const float4* ad = (const float4*)(a + (size_t)h * 1024 + 512 + lane * 8);
  float4 a0 = as[0], a1 = as[1];
  float4 b0 = ad[0], b1 = ad[1];
  float s1 = z0.x*a0.x + z0.y*a0.y + z0.z*a0.z + z0.w*a0.w
           + z1.x*a1.x + z1.y*a1.y + z1.z*a1.z + z1.w*a1.w;
  float s2 = z0.x*b0.x + z0.y*b0.y + z0.z*b0.z + z0.w*b0.w
           + z1.x*b1.x + z1.y*b1.y + z1.z*b1.z + z1.w*b1.w;
  s1 = wave_sum(s1);
  s2 = wave_sum(s2);
  if (lane == 0) { ssrc[idx] = s1; sdst[idx] = s2; }
}

// ---------------------------------------------------------------------------
// CSR build (dst shared across all 4 layers)
// ---------------------------------------------------------------------------
__global__ void count_k(const int* __restrict__ dst, int* __restrict__ cnt) {
  int e = blockIdx.x * 256 + threadIdx.x;
  if (e < N_EDGES) atomicAdd(&cnt[dst[e]], 1);
}

__global__ __launch_bounds__(256) void scan_k(
    const int* __restrict__ cnt, int* __restrict__ offs, int* __restrict__ cur)
{
  __shared__ int part[256];
  int t = threadIdx.x;
  int loc[8]; int s = 0;
  #pragma unroll
  for (int j = 0; j < 8; ++j) { loc[j] = s; s += cnt[t * 8 + j]; }
  part[t] = s;
  __syncthreads();
  for (int d = 1; d < 256; d <<= 1) {
    int v = (t >= d) ? part[t - d] : 0;
    __syncthreads();
    part[t] += v;
    __syncthreads();
  }
  int base = (t == 0) ? 0 : part[t - 1];
  #pragma unroll
  for (int j = 0; j < 8; ++j) {
    int o = base + loc[j];
    offs[t * 8 + j] = o;
    cur[t * 8 + j]  = o;
  }
  if (t == 255) offs[2048] = part[255];
}

__global__ void scatter_k(const int* __restrict__ dst, const int* __restrict__ srcv,
                          int* __restrict__ cur, int* __restrict__ esrc) {
  int e = blockIdx.x * 256 + threadIdx.x;
  if (e < N_EDGES) {
    int p = atomicAdd(&cur[dst[e]], 1);
    esrc[p] = srcv[e];
  }
}

// ---------------------------------------------------------------------------
// Fused softmax-attention + aggregation. One wave per (n, h).
// ---------------------------------------------------------------------------
__global__ __launch_bounds__(64) void attn_agg(
    const float* __restrict__ z, const float* __restrict__ ssrc,
    const float* __restrict__ sdst, const int* __restrict__ offs,
    const int* __restrict__ esrc, unsigned short* __restrict__ outb,
    float* __restrict__ outf, int H)
{
  const int n = blockIdx.x, h = blockIdx.y, lane = threadIdx.x;
  const int s0 = offs[n], s1 = offs[n + 1];
  const float sd = sdst[n * H + h];

  float m = -3e38f;
  for (int i = s0 + lane; i < s1; i += 64) {
    float s = ssrc[esrc[i] * H + h] + sd;
    s = (s > 0.f) ? s : s * 0.01f;
    m = fmaxf(m, s);
  }
  m = wave_max(m);

  float den = 0.f;
  for (int i = s0 + lane; i < s1; i += 64) {
    float s = ssrc[esrc[i] * H + h] + sd;
    s = (s > 0.f) ? s : s * 0.01f;
    den += __expf(s - m);
  }
  den = wave_sum(den);
  const float inv = 1.f / den;

  float acc[8] = {0.f, 0.f, 0.f, 0.f, 0.f, 0.f, 0.f, 0.f};
  const float* zb = z + (size_t)h * 512 + lane * 8;
  for (int i = s0; i < s1; ++i) {
    int se = esrc[i];
    float s = ssrc[se * H + h] + sd;
    s = (s > 0.f) ? s : s * 0.01f;
    float alpha = __expf(s - m) * inv;
    const float4* zr = (const float4*)(zb + (size_t)se * H * 512);
    float4 q0 = zr[0], q1 = zr[1];
    acc[0] += alpha * q0.x; acc[1] += alpha * q0.y;
    acc[2] += alpha * q0.z; acc[3] += alpha * q0.w;
    acc[4] += alpha * q1.x; acc[5] += alpha * q1.y;
    acc[6] += alpha * q1.z; acc[7] += alpha * q1.w;
  }

  const size_t base = (size_t)n * H * 512 + h * 512 + lane * 8;
  if (outf) {
    float4 o0 = {acc[0], acc[1], acc[2], acc[3]};
    float4 o1 = {acc[4], acc[5], acc[6], acc[7]};
    *(float4*)(outf + base)     = o0;
    *(float4*)(outf + base + 4) = o1;
  } else {
    uint4 pk;
    pk.x = (unsigned)f2bf(acc[0]) | ((unsigned)f2bf(acc[1]) << 16);
    pk.y = (unsigned)f2bf(acc[2]) | ((unsigned)f2bf(acc[3]) << 16);
    pk.z = (unsigned)f2bf(acc[4]) | ((unsigned)f2bf(acc[5]) << 16);
    pk.w = (unsigned)f2bf(acc[6]) | ((unsigned)f2bf(acc[7]) << 16);
    *(uint4*)(outb + base) = pk;
  }
}

// ---------------------------------------------------------------------------
extern "C" void kernel_launch(void* const* d_in, const int* in_sizes, int n_in,
                              void* d_out, int out_size, void* d_ws, size_t ws_size,
                              hipStream_t stream)
{
  (void)in_sizes; (void)n_in; (void)out_size;
  const float* feat = (const float*)d_in[0];
  const float* W1   = (const float*)d_in[1];
  const float* a1   = (const float*)d_in[2];
  const float* W2   = (const float*)d_in[3];
  const float* a2   = (const float*)d_in[4];
  const float* W3   = (const float*)d_in[5];
  const float* a3   = (const float*)d_in[6];
  const float* W4   = (const float*)d_in[7];
  const float* a4   = (const float*)d_in[8];
  const int* src = (const int*)d_in[9];
  const int* dst = (const int*)d_in[10];
  float* out = (float*)d_out;

  const size_t WT16 = (size_t)16 * 512 * 8192 * 2;      // 134,217,728
  const size_t WT8  = WT16 / 2;
  const size_t ZSZ  = (size_t)N_NODES * 16 * 512 * 4;   // 67,108,864
  const size_t XSZ  = (size_t)N_NODES * 8192 * 2;       // 33,554,432
  const size_t X0SZ = (size_t)N_NODES * 512 * 2;        //  2,097,152
  const size_t SMALL = 131072 + 131072 + 8192 + 8448 + 8192 + 131072;
  const size_t NEED16 = WT16 + ZSZ + XSZ + X0SZ + SMALL;

  const int ngroups = (ws_size >= NEED16) ? 1 : 2;
  const size_t wtsz = (ngroups == 1) ? WT16 : WT8;

  char* ws = (char*)d_ws;
  unsigned short* wt = (unsigned short*)ws;
  float* z           = (float*)(ws + wtsz);
  unsigned short* x  = (unsigned short*)(ws + wtsz + ZSZ);
  unsigned short* x0 = (unsigned short*)(ws + wtsz + ZSZ + XSZ);
  char* sm           = ws + wtsz + ZSZ + XSZ + X0SZ;
  float* ssrc        = (float*)(sm);
  float* sdst        = (float*)(sm + 131072);
  int* cnt           = (int*)(sm + 262144);
  int* offs          = (int*)(sm + 270336);
  int* cur           = (int*)(sm + 278784);
  int* esrc          = (int*)(sm + 286976);

  // CSR by dst (constant across layers)
  hipMemsetAsync(cnt, 0, N_NODES * sizeof(int), stream);
  count_k<<<N_EDGES / 256, 256, 0, stream>>>(dst, cnt);
  scan_k<<<1, 256, 0, stream>>>(cnt, offs, cur);
  scatter_k<<<N_EDGES / 256, 256, 0, stream>>>(dst, src, cur, esrc);

  // feat fp32 -> bf16
  cast_feat<<<1024, 256, 0, stream>>>(feat, x0, N_NODES * 512 / 4);

  // Big-layer GEMM via the phased 256^2 kernel.
  auto run_big = [&](const float* W, const unsigned short* xin, int Fin) {
    const int hpg = 16 / ngroups;
    for (int g = 0; g < ngroups; ++g) {
      transpose_w<<<dim3(Fin / 64, 8, hpg), 256, 0, stream>>>(
          W + (size_t)g * hpg * Fin * 512, wt, Fin);
      const int ntn = hpg * 2;  // N = hpg*512, 256-wide tiles
      gemm8<<<dim3(8 * ntn), 512, 0, stream>>>(
          xin, wt, z, Fin, 8192, g * hpg * 512);
    }
  };

  // Layer 1: Fin=512, H=16 (wt for all 16 heads = 8.4 MB, always fits)
  transpose_w<<<dim3(8, 8, 16), 256, 0, stream>>>(W1, wt, 512);
  gemm8<<<dim3(8 * 32), 512, 0, stream>>>(x0, wt, z, 512, 8192, 0);
  sdot_kernel<<<N_NODES * 16, 64, 0, stream>>>(z, a1, ssrc, sdst, 16);
  attn_agg<<<dim3(N_NODES, 16), 64, 0, stream>>>(z, ssrc, sdst, offs, esrc,
                                                 x, nullptr, 16);

  // Layer 2: Fin=8192, H=16
  run_big(W2, x, 8192);
  sdot_kernel<<<N_NODES * 16, 64, 0, stream>>>(z, a2, ssrc, sdst, 16);
  attn_agg<<<dim3(N_NODES, 16), 64, 0, stream>>>(z, ssrc, sdst, offs, esrc,
                                                 x, nullptr, 16);

  // Layer 3: Fin=8192, H=16
  run_big(W3, x, 8192);
  sdot_kernel<<<N_NODES * 16, 64, 0, stream>>>(z, a3, ssrc, sdst, 16);
  attn_agg<<<dim3(N_NODES, 16), 64, 0, stream>>>(z, ssrc, sdst, offs, esrc,
                                                 x, nullptr, 16);

  // Layer 4: Fin=8192, H=1 — old 128^2 path, split-K x8 (512 blocks, atomicAdd)
  transpose_w<<<dim3(128, 8, 1), 256, 0, stream>>>(W4, wt, 8192);
  hipMemsetAsync(z, 0, (size_t)N_NODES * 512 * sizeof(float), stream);
  gemm_bt<<<dim3(16, 4, 8), 256, 0, stream>>>(x, wt, z, 8192, 512, 0, 1024);
  sdot_kernel<<<N_NODES, 64, 0, stream>>>(z, a4, ssrc, sdst, 1);
  attn_agg<<<dim3(N_NODES, 1), 64, 0, stream>>>(z, ssrc, sdst, offs, esrc,
                                                nullptr, out, 1);
}